// Round 2
// baseline (638.392 us; speedup 1.0000x reference)
//
#include <hip/hip_runtime.h>
#include <math.h>

#define N 1024
#define NB 256
#define NT 1024
#define KD 5

// ---------------- wave / block reductions (wave = 64) ----------------
__device__ __forceinline__ float wred_sum(float v){
#pragma unroll
  for (int off = 32; off > 0; off >>= 1) v += __shfl_down(v, off);
  return v;
}
__device__ __forceinline__ float wred_max(float v){
#pragma unroll
  for (int off = 32; off > 0; off >>= 1) v = fmaxf(v, __shfl_down(v, off));
  return v;
}
// 1024-thread block sum/max, result broadcast to all threads.
__device__ __forceinline__ float bsum(float v, volatile float* s16){
  float w = wred_sum(v);
  __syncthreads();                       // protect s16 reuse from previous call
  if ((threadIdx.x & 63) == 0) s16[threadIdx.x >> 6] = w;
  __syncthreads();
  float r = 0.f;
#pragma unroll
  for (int i = 0; i < 16; ++i) r += s16[i];
  return r;
}
__device__ __forceinline__ float bmax(float v, volatile float* s16){
  float w = wred_max(v);
  __syncthreads();
  if ((threadIdx.x & 63) == 0) s16[threadIdx.x >> 6] = w;
  __syncthreads();
  float r = s16[0];
#pragma unroll
  for (int i = 1; i < 16; ++i) r = fmaxf(r, s16[i]);
  return r;
}

// ---------------- software grid barrier (256 co-resident blocks) ----------------
// Each call site uses a fresh counter slot (zeroed by memset before launch).
__device__ __forceinline__ void gbar(int* c, int nb){
  __syncthreads();                       // all block stores drained to L2
  if (threadIdx.x == 0){
    __threadfence();                     // release: write back L2 (device scope)
    atomicAdd(c, 1);                     // device-scope atomic
    while (__hip_atomic_load(c, __ATOMIC_RELAXED, __HIP_MEMORY_SCOPE_AGENT) < nb){
      __builtin_amdgcn_s_sleep(8);
    }
    __threadfence();                     // acquire: invalidate L1/L2
  }
  __syncthreads();
}

// ---------------- the fused persistent kernel ----------------
// Block B owns rows 4B..4B+3; thread t owns column t.
extern "C" __global__ void __launch_bounds__(NT, 1)
gm_mega(const int* __restrict__ adj1, const int* __restrict__ adj2,
        const float* __restrict__ roW1, const float* __restrict__ roB1,
        const float* __restrict__ roW2, const float* __restrict__ roB2,
        const float* __restrict__ fW1,  const float* __restrict__ fB1,
        const float* __restrict__ fW2,  const float* __restrict__ fB2,
        float* __restrict__ t0, float* __restrict__ t1,
        float* __restrict__ P,  float* __restrict__ Csum,
        float* __restrict__ Rg, int* __restrict__ cnt,
        float* __restrict__ out)
{
  __shared__ __align__(16) float rows2[NT * 8];   // 32 KB: gathered t-rows, [j*8 + r]
  __shared__ float sd1[NT];
  __shared__ float s16[16];
  __shared__ float ux[64], udA[64], udB[64];      // PWL unsorted
  __shared__ float xs_s[64], dA_s[64], dB_s[64];  // PWL sorted
  __shared__ float A_tab[65], B_tab[65];
  __shared__ float sA0B0[2];
  __shared__ float sAv[4];
  __shared__ float tab5[5];

  const int t = threadIdx.x;
  const int B = blockIdx.x;
  int barIdx = 0;

  // ---- adjacency rows kept in registers for the whole kernel ----
  int a2[KD];
#pragma unroll
  for (int c = 0; c < KD; ++c) a2[c] = adj2[t * KD + c];
  int a1v[KD];
#pragma unroll
  for (int r = 0; r < KD; ++r) a1v[r] = adj1[t * KD + r];

  // ---- degrees (distinct neighbor count) ----
  int c1 = 0;
#pragma unroll
  for (int r = 0; r < KD; ++r){
    bool dup = false;
#pragma unroll
    for (int s = 0; s < r; ++s) dup = dup || (a1v[s] == a1v[r]);
    c1 += dup ? 0 : 1;
  }
  sd1[t] = (float)c1;
  int c2 = 0;
#pragma unroll
  for (int r = 0; r < KD; ++r){
    bool dup = false;
#pragma unroll
    for (int s = 0; s < r; ++s) dup = dup || (a2[s] == a2[r]);
    c2 += dup ? 0 : 1;
  }
  const float d2loc = (float)c2;

  const float tt = bsum((float)c1, s16) * (1.0f / 1024.0f);   // ttheta (exact: int sum)

  // ---- layer-0 MLP: only 5 distinct inputs -> exact table ----
  if (t < KD){
    float x = -(float)t / tt;
    float acc = roB2[0];
    for (int k = 0; k < 64; ++k){
      float h = fmaxf(fmaf(x, roW1[k], roB1[k]), 0.f);
      acc = fmaf(h, roW2[k], acc);
    }
    tab5[t] = acc;
  }
  __syncthreads();

  // ---- layer-0 row softmax: t0 = y - rowmax, E regs, Rloc = 1/rowsum ----
  float Ereg[4], Rloc[4];
  float yF[4], rmF[4], rsiF[4];
#pragma unroll
  for (int r = 0; r < 4; ++r){ yF[r] = 0.f; rmF[r] = 0.f; rsiF[r] = 1.f; }
  {
    float y0[4];
#pragma unroll
    for (int r = 0; r < 4; ++r){
      float diff = fabsf(sd1[4 * B + r] - d2loc);
      y0[r] = tab5[(int)diff];
    }
#pragma unroll
    for (int r = 0; r < 4; ++r){
      float rm = bmax(y0[r], s16);
      float tv = y0[r] - rm;
      t0[(size_t)(4 * B + r) * N + t] = tv;
      float e = expf(tv);
      Ereg[r] = e;
      Rloc[r] = 1.0f / bsum(e, s16);
    }
  }

  const float* tcur = t0;
  float* tnx = t1;

  for (int li = 0; li < 3; ++li){
    // ---- sinkhorn: col,row,col,row,col (row-softmax init already folded in) ----
#pragma unroll 1
    for (int pass = 0; pass < 3; ++pass){
      // col pass partials: cp[t] = sum_r E[r][t] * Rloc[r]
      float cp = 0.f;
#pragma unroll
      for (int r = 0; r < 4; ++r) cp = fmaf(Ereg[r], Rloc[r], cp);
      P[(size_t)B * N + t] = cp;
      gbar(&cnt[barIdx++], NB);
      // col reduce: block B owns cols 4B..4B+3
      {
        int k = t & 255;
        float v = P[(size_t)k * N + 4 * B + (t >> 8)];
        float w = wred_sum(v);
        __syncthreads();
        if ((t & 63) == 0) s16[t >> 6] = w;
        __syncthreads();
        if ((t & 255) == 0){
          int cc = t >> 8;
          Csum[4 * B + cc] = s16[4 * cc] + s16[4 * cc + 1] + s16[4 * cc + 2] + s16[4 * cc + 3];
        }
      }
      gbar(&cnt[barIdx++], NB);
      if (pass < 2){
        float Cl = Csum[t];
#pragma unroll
        for (int r = 0; r < 4; ++r){
          float q = Ereg[r] / Cl;
          Rloc[r] = 1.0f / bsum(q, s16);
        }
        if (pass == 1 && t < 4) Rg[4 * B + t] = Rloc[t];   // final R for the A-gather
      }
    }

    // ---- A/B log terms (local only): Bvl per thread-col, sAv per block-row ----
    float Bvl = 0.f;
#pragma unroll
    for (int c = 0; c < KD; ++c) Bvl -= logf(Csum[a2[c]]);
    if (t < 4){
      int a = 4 * B + t;
      float s = 5.0f * logf(1536.0f);
#pragma unroll
      for (int r = 0; r < KD; ++r) s += logf(Rg[adj1[a * KD + r]]);
      sAv[t] = s;
    }

    // ---- build PWL tables for the next MLP ----
    const float* w1g = (li < 2) ? (roW1 + (li + 1) * 64) : fW1;
    const float* b1g = (li < 2) ? (roB1 + (li + 1) * 64) : fB1;
    const float* w2g = (li < 2) ? (roW2 + (li + 1) * 64) : fW2;
    const float* b2g = (li < 2) ? (roB2 + (li + 1))      : fB2;
    if (t < 64){
      float w1 = w1g[t], bb = b1g[t], w2 = w2g[t];
      float xk, sdA, sdB, a0t = 0.f, b0t = 0.f;
      if (w1 != 0.f){
        xk = -bb / w1;
        float dA = w1 * w2, dB = bb * w2;
        if (w1 > 0.f){ sdA = dA;  sdB = dB; }
        else         { sdA = -dA; sdB = -dB; a0t = dA; b0t = dB; }
      } else {
        xk = 3.0e38f; sdA = 0.f; sdB = 0.f;
        b0t = fmaxf(bb, 0.f) * w2;
      }
      ux[t] = xk; udA[t] = sdA; udB[t] = sdB;
      float A0 = wred_sum(a0t);
      float B0 = wred_sum(b0t);
      if (t == 0){ sA0B0[0] = A0; sA0B0[1] = B0 + b2g[0]; }
    }
    __syncthreads();
    if (t < 64){
      float xk = ux[t]; int rank = 0;
      for (int j = 0; j < 64; ++j){
        float xj = ux[j];
        rank += (xj < xk || (xj == xk && j < t)) ? 1 : 0;
      }
      xs_s[rank] = ux[t]; dA_s[rank] = udA[t]; dB_s[rank] = udB[t];
    }
    __syncthreads();
    if (t < 65){
      float sa = sA0B0[0], sb = sA0B0[1];
      for (int r = 0; r < t; ++r){ sa += dA_s[r]; sb += dB_s[r]; }
      A_tab[t] = sa; B_tab[t] = sb;
    }
    __syncthreads();

    // ---- X1 phase: 4 owned rows sequentially; fused next-layer MLP + row stats ----
    float Enew[4] = {0.f, 0.f, 0.f, 0.f};
    float Rnew[4] = {1.f, 1.f, 1.f, 1.f};
#pragma unroll 1
    for (int rr = 0; rr < 4; ++rr){
      int a = 4 * B + rr;
      int s0 = adj1[a * KD + 0], s1 = adj1[a * KD + 1], s2 = adj1[a * KD + 2],
          s3 = adj1[a * KD + 3], s4 = adj1[a * KD + 4];
      __syncthreads();   // previous iteration's readers done with rows2
      rows2[t * 8 + 0] = tcur[(size_t)s0 * N + t];
      rows2[t * 8 + 1] = tcur[(size_t)s1 * N + t];
      rows2[t * 8 + 2] = tcur[(size_t)s2 * N + t];
      rows2[t * 8 + 3] = tcur[(size_t)s3 * N + t];
      rows2[t * 8 + 4] = tcur[(size_t)s4 * N + t];
      __syncthreads();
      // gather 5x5 tile (b128 + b32 per column)
      float t5[KD][KD];
#pragma unroll
      for (int c = 0; c < KD; ++c){
        const float4 q = *(const float4*)(&rows2[a2[c] * 8]);
        float q4 = rows2[a2[c] * 8 + 4];
        t5[0][c] = q.x; t5[1][c] = q.y; t5[2][c] = q.z; t5[3][c] = q.w; t5[4][c] = q4;
      }
      // subset-DP assignment max
      float f[32];
      f[0] = 0.f;
#pragma unroll
      for (int m = 1; m < 32; ++m){
        int r = __popc(m) - 1;
        float best = -3.0e38f;
#pragma unroll
        for (int c = 0; c < KD; ++c)
          if (m & (1 << c)) best = fmaxf(best, f[m ^ (1 << c)] + t5[r][c]);
        f[m] = best;
      }
      float X1v = sAv[rr] + Bvl + f[31];
      float x = (li < 2) ? (X1v / tt) : X1v;
      // PWL eval: seg = #breakpoints <= x, then y = A*x + B
      int seg = 0;
#pragma unroll
      for (int s = 64; s; s >>= 1)
        if (seg + s <= 64 && xs_s[seg + s - 1] <= x) seg += s;
      float y = fmaf(A_tab[seg], x, B_tab[seg]);

      float rm = bmax(y, s16);
      float e = expf(y - rm);
      float rs = bsum(e, s16);
      if (li < 2){
        tnx[(size_t)a * N + t] = y - rm;
        Enew[rr] = e; Rnew[rr] = 1.0f / rs;
      } else {
        yF[rr] = y; rmF[rr] = rm; rsiF[rr] = 1.0f / rs;
      }
    }
    if (li < 2){
#pragma unroll
      for (int r = 0; r < 4; ++r){ Ereg[r] = Enew[r]; Rloc[r] = Rnew[r]; }
    }
    const float* tmp = tcur; tcur = tnx; tnx = (float*)tmp;
  }

  // ---- final masked softmax: col denominators from yF regs, then combine ----
  {
    float cp = 0.f;
#pragma unroll
    for (int r = 0; r < 4; ++r) cp += expf(yF[r]);
    P[(size_t)B * N + t] = cp;
    gbar(&cnt[barIdx++], NB);
    {
      int k = t & 255;
      float v = P[(size_t)k * N + 4 * B + (t >> 8)];
      float w = wred_sum(v);
      __syncthreads();
      if ((t & 63) == 0) s16[t >> 6] = w;
      __syncthreads();
      if ((t & 255) == 0){
        int cc = t >> 8;
        Csum[4 * B + cc] = s16[4 * cc] + s16[4 * cc + 1] + s16[4 * cc + 2] + s16[4 * cc + 3];
      }
    }
    gbar(&cnt[barIdx++], NB);
    float Cl = Csum[t];
#pragma unroll
    for (int r = 0; r < 4; ++r){
      float yv = yF[r];
      float v = 0.5f * (expf(yv - rmF[r]) * rsiF[r] + expf(yv) / Cl);
      out[(size_t)(4 * B + r) * N + t] = v;
    }
  }
}

extern "C" void kernel_launch(void* const* d_in, const int* in_sizes, int n_in,
                              void* d_out, int out_size, void* d_ws, size_t ws_size,
                              hipStream_t stream){
  (void)in_sizes; (void)n_in; (void)out_size; (void)ws_size;
  const int*   adj1 = (const int*)d_in[2];
  const int*   adj2 = (const int*)d_in[3];
  const float* roW1 = (const float*)d_in[4];
  const float* roB1 = (const float*)d_in[5];
  const float* roW2 = (const float*)d_in[6];
  const float* roB2 = (const float*)d_in[7];
  const float* fW1  = (const float*)d_in[8];
  const float* fB1  = (const float*)d_in[9];
  const float* fW2  = (const float*)d_in[10];
  const float* fB2  = (const float*)d_in[11];
  float* out = (float*)d_out;

  // ws layout: t0 (4MB) | t1 (4MB) | P (1MB) | Csum 4KB | Rg 4KB | cnt 128B
  float* t0   = (float*)d_ws;
  float* t1   = t0 + (size_t)N * N;
  float* P    = t1 + (size_t)N * N;
  float* Csum = P + (size_t)NB * N;
  float* Rg   = Csum + N;
  int*   cnt  = (int*)(Rg + N);

  hipMemsetAsync(cnt, 0, 32 * sizeof(int), stream);
  gm_mega<<<NB, NT, 0, stream>>>(adj1, adj2, roW1, roB1, roW2, roB2,
                                 fW1, fB1, fW2, fB2,
                                 t0, t1, P, Csum, Rg, cnt, out);
}

// Round 3
// 240.686 us; speedup vs baseline: 2.6524x; 2.6524x over previous
//
#include <hip/hip_runtime.h>
#include <math.h>

#define N 1024
#define KD 5

// ---------------- wave (64-lane) reductions ----------------
__device__ __forceinline__ float wred_sum(float v){
#pragma unroll
  for (int off = 32; off > 0; off >>= 1) v += __shfl_down(v, off);
  return v;
}
__device__ __forceinline__ float wred_max(float v){
#pragma unroll
  for (int off = 32; off > 0; off >>= 1) v = fmaxf(v, __shfl_down(v, off));
  return v;
}

// ---- batch-of-4 block reductions over 1024 threads (16 waves); broadcast results ----
__device__ __forceinline__ void bsum4(float v[4], float* s64){
  float w0 = wred_sum(v[0]), w1 = wred_sum(v[1]), w2 = wred_sum(v[2]), w3 = wred_sum(v[3]);
  __syncthreads();
  int wv = threadIdx.x >> 6;
  if ((threadIdx.x & 63) == 0){ s64[wv*4] = w0; s64[wv*4+1] = w1; s64[wv*4+2] = w2; s64[wv*4+3] = w3; }
  __syncthreads();
  float r0 = 0.f, r1 = 0.f, r2 = 0.f, r3 = 0.f;
#pragma unroll
  for (int i = 0; i < 16; ++i){ r0 += s64[i*4]; r1 += s64[i*4+1]; r2 += s64[i*4+2]; r3 += s64[i*4+3]; }
  v[0] = r0; v[1] = r1; v[2] = r2; v[3] = r3;
}
__device__ __forceinline__ void bmax4(float v[4], float* s64){
  float w0 = wred_max(v[0]), w1 = wred_max(v[1]), w2 = wred_max(v[2]), w3 = wred_max(v[3]);
  __syncthreads();
  int wv = threadIdx.x >> 6;
  if ((threadIdx.x & 63) == 0){ s64[wv*4] = w0; s64[wv*4+1] = w1; s64[wv*4+2] = w2; s64[wv*4+3] = w3; }
  __syncthreads();
  float r0 = s64[0], r1 = s64[1], r2 = s64[2], r3 = s64[3];
#pragma unroll
  for (int i = 1; i < 16; ++i){
    r0 = fmaxf(r0, s64[i*4]); r1 = fmaxf(r1, s64[i*4+1]);
    r2 = fmaxf(r2, s64[i*4+2]); r3 = fmaxf(r3, s64[i*4+3]);
  }
  v[0] = r0; v[1] = r1; v[2] = r2; v[3] = r3;
}

// ---- batch-of-2 block reductions over 512 threads (8 waves); broadcast results ----
__device__ __forceinline__ void bsum2(float v[2], float* s16){
  float w0 = wred_sum(v[0]), w1 = wred_sum(v[1]);
  __syncthreads();
  int wv = threadIdx.x >> 6;
  if ((threadIdx.x & 63) == 0){ s16[wv*2] = w0; s16[wv*2+1] = w1; }
  __syncthreads();
  float r0 = 0.f, r1 = 0.f;
#pragma unroll
  for (int i = 0; i < 8; ++i){ r0 += s16[i*2]; r1 += s16[i*2+1]; }
  v[0] = r0; v[1] = r1;
}
__device__ __forceinline__ void bmax2(float v[2], float* s16){
  float w0 = wred_max(v[0]), w1 = wred_max(v[1]);
  __syncthreads();
  int wv = threadIdx.x >> 6;
  if ((threadIdx.x & 63) == 0){ s16[wv*2] = w0; s16[wv*2+1] = w1; }
  __syncthreads();
  float r0 = s16[0], r1 = s16[1];
#pragma unroll
  for (int i = 1; i < 8; ++i){ r0 = fmaxf(r0, s16[i*2]); r1 = fmaxf(r1, s16[i*2+1]); }
  v[0] = r0; v[1] = r1;
}

// ---------------- init: d1 degrees + ttheta ----------------
__global__ __launch_bounds__(1024) void k_init(const int* __restrict__ adj1,
                                               float* __restrict__ d1,
                                               float* __restrict__ ttv){
  __shared__ float s16[16];
  int t = threadIdx.x;
  int v[KD];
#pragma unroll
  for (int r = 0; r < KD; ++r) v[r] = adj1[t * KD + r];
  int c1 = 0;
#pragma unroll
  for (int r = 0; r < KD; ++r){
    bool dup = false;
#pragma unroll
    for (int s = 0; s < r; ++s) dup = dup || (v[s] == v[r]);
    c1 += dup ? 0 : 1;
  }
  d1[t] = (float)c1;
  float w = wred_sum((float)c1);
  if ((t & 63) == 0) s16[t >> 6] = w;
  __syncthreads();
  if (t == 0){
    float s = 0.f;
    for (int i = 0; i < 16; ++i) s += s16[i];
    ttv[0] = s * (1.0f / 1024.0f);
  }
}

// ---------------- layer-0 producer: t0 = y0 - rowmax, and C1 += E*R0 ----------------
__global__ __launch_bounds__(1024) void k_row0(const int* __restrict__ adj2,
                                               const float* __restrict__ d1,
                                               const float* __restrict__ ttv,
                                               const float* __restrict__ roW1,
                                               const float* __restrict__ roB1,
                                               const float* __restrict__ roW2,
                                               const float* __restrict__ roB2,
                                               float* __restrict__ t0,
                                               float* __restrict__ C1){
  __shared__ float s64[64];
  __shared__ float tab5[8];
  __shared__ float sd1r[4];
  int t = threadIdx.x, B = blockIdx.x;
  int a2[KD];
#pragma unroll
  for (int c = 0; c < KD; ++c) a2[c] = adj2[t * KD + c];
  int c2 = 0;
#pragma unroll
  for (int r = 0; r < KD; ++r){
    bool dup = false;
#pragma unroll
    for (int s = 0; s < r; ++s) dup = dup || (a2[s] == a2[r]);
    c2 += dup ? 0 : 1;
  }
  float tt = ttv[0];
  if (t < KD){                       // exact 5-entry layer-0 MLP table
    float x = -(float)t / tt;
    float acc = roB2[0];
    for (int k = 0; k < 64; ++k){
      float h = fmaxf(fmaf(x, roW1[k], roB1[k]), 0.f);
      acc = fmaf(h, roW2[k], acc);
    }
    tab5[t] = acc;
  }
  if (t < 4) sd1r[t] = d1[4 * B + t];
  __syncthreads();
  float y0[4], rm[4];
#pragma unroll
  for (int r = 0; r < 4; ++r){
    y0[r] = tab5[(int)fabsf(sd1r[r] - (float)c2)];
    rm[r] = y0[r];
  }
  bmax4(rm, s64);
  float e[4], q[4];
#pragma unroll
  for (int r = 0; r < 4; ++r){
    float tv = y0[r] - rm[r];
    t0[(size_t)(4 * B + r) * N + t] = tv;
    e[r] = expf(tv);
    q[r] = e[r];
  }
  bsum4(q, s64);
  float cp = 0.f;
#pragma unroll
  for (int r = 0; r < 4; ++r) cp += e[r] / q[r];
  atomicAdd(&C1[t], cp);
}

// ---------------- fused sinkhorn pass: row renorm with Cin, emit Cout += E*R' ----------------
__global__ __launch_bounds__(1024) void kAB(const float* __restrict__ tm,
                                            const float* __restrict__ Cin,
                                            float* __restrict__ Cout,
                                            float* __restrict__ Rg,
                                            int writeRg){
  __shared__ float s64[64];
  int t = threadIdx.x, B = blockIdx.x;
  float Cl = Cin[t];
  float e[4], q[4];
#pragma unroll
  for (int r = 0; r < 4; ++r){
    e[r] = expf(tm[(size_t)(4 * B + r) * N + t]);
    q[r] = e[r] / Cl;
  }
  bsum4(q, s64);                      // q[r] = rowsum of E/Cin for row 4B+r
  float cp = 0.f;
#pragma unroll
  for (int r = 0; r < 4; ++r) cp += e[r] / q[r];
  atomicAdd(&Cout[t], cp);
  if (writeRg && t < 4) Rg[4 * B + t] = 1.0f / q[t];
}

// ---------------- 5x5 assignment-max via subset DP ----------------
__device__ __forceinline__ float dp5(const float* __restrict__ rowsBase, const int* __restrict__ a2){
  float t5[KD][KD];
#pragma unroll
  for (int r = 0; r < KD; ++r)
#pragma unroll
    for (int c = 0; c < KD; ++c) t5[r][c] = rowsBase[r * N + a2[c]];
  float f[32];
  f[0] = 0.f;
#pragma unroll
  for (int m = 1; m < 32; ++m){
    int r = __popc(m) - 1;
    float best = -3.0e38f;
#pragma unroll
    for (int c = 0; c < KD; ++c)
      if (m & (1 << c)) best = fmaxf(best, f[m ^ (1 << c)] + t5[r][c]);
    f[m] = best;
  }
  return f[31];
}

// ---------------- X1 + fused next MLP (PWL) + row stats + next-C partials ----------------
// 512 blocks x 512 threads; block owns rows 2B,2B+1; thread owns cols t, t+512.
__global__ __launch_bounds__(512, 4) void
kX1(const float* __restrict__ tm, const int* __restrict__ adj1, const int* __restrict__ adj2,
    const float* __restrict__ Rg, const float* __restrict__ C3, const float* __restrict__ ttv,
    const float* __restrict__ w1g, const float* __restrict__ b1g,
    const float* __restrict__ w2g, const float* __restrict__ b2g,
    int isFinal, float* __restrict__ tnx, float* __restrict__ Cout,
    float* __restrict__ rmF, float* __restrict__ rsF){
  __shared__ __align__(16) float rows[10 * N];   // 40 KB, [r][N] conflict-free layout
  __shared__ float lc[N];                        // log C3
  __shared__ float s16[16];
  __shared__ float ux[64], udA[64], udB[64], xs_s[64], dA_s[64], dB_s[64];
  __shared__ float A_tab[65], B_tab[65], sA0B0[2], sAv[2];
  int t = threadIdx.x, B = blockIdx.x;

  int a2a[KD], a2b[KD];
#pragma unroll
  for (int c = 0; c < KD; ++c){ a2a[c] = adj2[t * KD + c]; a2b[c] = adj2[(t + 512) * KD + c]; }
  lc[t] = logf(C3[t]);
  lc[t + 512] = logf(C3[t + 512]);
#pragma unroll
  for (int r2 = 0; r2 < 10; ++r2){
    int src = adj1[(2 * B + (r2 / 5)) * KD + (r2 % 5)];   // wave-uniform
    rows[r2 * N + t]       = tm[(size_t)src * N + t];
    rows[r2 * N + t + 512] = tm[(size_t)src * N + t + 512];
  }
  if (t < 2){
    int a = 2 * B + t;
    float s = 5.0f * logf(1536.0f);
#pragma unroll
    for (int r = 0; r < KD; ++r) s += logf(Rg[adj1[a * KD + r]]);
    sAv[t] = s;
  }
  // PWL table build (wave 0)
  if (t < 64){
    float w1 = w1g[t], bb = b1g[t], w2 = w2g[t];
    float xk, sdA, sdB, a0t = 0.f, b0t = 0.f;
    if (w1 != 0.f){
      xk = -bb / w1;
      float dA = w1 * w2, dB = bb * w2;
      if (w1 > 0.f){ sdA = dA;  sdB = dB; }
      else         { sdA = -dA; sdB = -dB; a0t = dA; b0t = dB; }
    } else {
      xk = 3.0e38f; sdA = 0.f; sdB = 0.f;
      b0t = fmaxf(bb, 0.f) * w2;
    }
    ux[t] = xk; udA[t] = sdA; udB[t] = sdB;
    float A0 = wred_sum(a0t);
    float B0 = wred_sum(b0t);
    if (t == 0){ sA0B0[0] = A0; sA0B0[1] = B0 + b2g[0]; }
  }
  __syncthreads();
  if (t < 64){
    float xk = ux[t]; int rank = 0;
    for (int j = 0; j < 64; ++j){
      float xj = ux[j];
      rank += (xj < xk || (xj == xk && j < t)) ? 1 : 0;
    }
    xs_s[rank] = ux[t]; dA_s[rank] = udA[t]; dB_s[rank] = udB[t];
  }
  __syncthreads();
  if (t < 65){
    float sa = sA0B0[0], sb = sA0B0[1];
    for (int r = 0; r < t; ++r){ sa += dA_s[r]; sb += dB_s[r]; }
    A_tab[t] = sa; B_tab[t] = sb;
  }
  __syncthreads();

  float tt = ttv[0];
  float Bv0 = -(lc[a2a[0]] + lc[a2a[1]] + lc[a2a[2]] + lc[a2a[3]] + lc[a2a[4]]);
  float Bv1 = -(lc[a2b[0]] + lc[a2b[1]] + lc[a2b[2]] + lc[a2b[3]] + lc[a2b[4]]);

  float y[2][2];
#pragma unroll
  for (int rr = 0; rr < 2; ++rr){
    const float* base = &rows[rr * 5 * N];
    float X0 = sAv[rr] + Bv0 + dp5(base, a2a);
    float X1 = sAv[rr] + Bv1 + dp5(base, a2b);
    float x0 = isFinal ? X0 : (X0 / tt);
    float x1 = isFinal ? X1 : (X1 / tt);
    int s0 = 0, s1 = 0;
#pragma unroll
    for (int s = 64; s; s >>= 1){
      if (s0 + s <= 64 && xs_s[s0 + s - 1] <= x0) s0 += s;
      if (s1 + s <= 64 && xs_s[s1 + s - 1] <= x1) s1 += s;
    }
    y[rr][0] = fmaf(A_tab[s0], x0, B_tab[s0]);
    y[rr][1] = fmaf(A_tab[s1], x1, B_tab[s1]);
  }
  float rm[2] = { fmaxf(y[0][0], y[0][1]), fmaxf(y[1][0], y[1][1]) };
  bmax2(rm, s16);
  float e[2][2], q[2];
#pragma unroll
  for (int rr = 0; rr < 2; ++rr){
    e[rr][0] = expf(y[rr][0] - rm[rr]);
    e[rr][1] = expf(y[rr][1] - rm[rr]);
    q[rr] = e[rr][0] + e[rr][1];
  }
  bsum2(q, s16);
  if (!isFinal){
    float cp0 = 0.f, cp1 = 0.f;
#pragma unroll
    for (int rr = 0; rr < 2; ++rr){
      size_t rowoff = (size_t)(2 * B + rr) * N;
      tnx[rowoff + t]       = y[rr][0] - rm[rr];
      tnx[rowoff + t + 512] = y[rr][1] - rm[rr];
      cp0 += e[rr][0] / q[rr];
      cp1 += e[rr][1] / q[rr];
    }
    atomicAdd(&Cout[t], cp0);
    atomicAdd(&Cout[t + 512], cp1);
  } else {
    float cp0 = 0.f, cp1 = 0.f;
#pragma unroll
    for (int rr = 0; rr < 2; ++rr){
      size_t rowoff = (size_t)(2 * B + rr) * N;
      tnx[rowoff + t]       = y[rr][0];
      tnx[rowoff + t + 512] = y[rr][1];
      cp0 += expf(y[rr][0]);
      cp1 += expf(y[rr][1]);
    }
    atomicAdd(&Cout[t], cp0);
    atomicAdd(&Cout[t + 512], cp1);
    if (t < 2){ rmF[2 * B + t] = rm[t]; rsF[2 * B + t] = q[t]; }
  }
}

// ---------------- final combine: 0.5*(row softmax + col softmax), in place ----------------
__global__ __launch_bounds__(1024) void k_combine(const float* __restrict__ y,
                                                  const float* __restrict__ rmF,
                                                  const float* __restrict__ rsF,
                                                  const float* __restrict__ cF,
                                                  float* __restrict__ out){
  int t = threadIdx.x, B = blockIdx.x;
  float Cl = cF[t];
#pragma unroll
  for (int r = 0; r < 4; ++r){
    int a = 4 * B + r;
    float yv = y[(size_t)a * N + t];
    float v = 0.5f * (expf(yv - rmF[a]) / rsF[a] + expf(yv) / Cl);
    out[(size_t)a * N + t] = v;
  }
}

extern "C" void kernel_launch(void* const* d_in, const int* in_sizes, int n_in,
                              void* d_out, int out_size, void* d_ws, size_t ws_size,
                              hipStream_t stream){
  (void)in_sizes; (void)n_in; (void)out_size; (void)ws_size;
  const int*   adj1 = (const int*)d_in[2];
  const int*   adj2 = (const int*)d_in[3];
  const float* roW1 = (const float*)d_in[4];
  const float* roB1 = (const float*)d_in[5];
  const float* roW2 = (const float*)d_in[6];
  const float* roB2 = (const float*)d_in[7];
  const float* fW1  = (const float*)d_in[8];
  const float* fB1  = (const float*)d_in[9];
  const float* fW2  = (const float*)d_in[10];
  const float* fB2  = (const float*)d_in[11];
  float* out = (float*)d_out;

  // ws: wsA (4MB) | Cpool 10*N | Rg N | d1 N | ttv 8 | rmF N | rsF N
  float* wsA   = (float*)d_ws;
  float* Cpool = wsA + (size_t)N * N;
  float* Rg    = Cpool + 10 * N;
  float* d1    = Rg + N;
  float* ttv   = d1 + N;
  float* rmF   = ttv + 8;
  float* rsF   = rmF + N;

  hipMemsetAsync(Cpool, 0, 10 * N * sizeof(float), stream);
  k_init<<<1, 1024, 0, stream>>>(adj1, d1, ttv);
  k_row0<<<256, 1024, 0, stream>>>(adj2, d1, ttv, roW1, roB1, roW2, roB2, wsA, Cpool);

  for (int li = 0; li < 3; ++li){
    const float* tcur = (li == 1) ? out : wsA;     // t0=wsA, t1=out, t2=wsA
    float* tnx        = (li == 1) ? wsA : out;
    float* Ca = Cpool + (size_t)(3 * li + 0) * N;
    float* Cb = Cpool + (size_t)(3 * li + 1) * N;
    float* Cc = Cpool + (size_t)(3 * li + 2) * N;
    kAB<<<256, 1024, 0, stream>>>(tcur, Ca, Cb, Rg, 0);
    kAB<<<256, 1024, 0, stream>>>(tcur, Cb, Cc, Rg, 1);
    int isFinal = (li == 2);
    const float* w1 = isFinal ? fW1 : roW1 + (li + 1) * 64;
    const float* b1 = isFinal ? fB1 : roB1 + (li + 1) * 64;
    const float* w2 = isFinal ? fW2 : roW2 + (li + 1) * 64;
    const float* b2 = isFinal ? fB2 : roB2 + (li + 1);
    float* CoutNext = isFinal ? (Cpool + (size_t)9 * N) : (Cpool + (size_t)(3 * li + 3) * N);
    kX1<<<512, 512, 0, stream>>>(tcur, adj1, adj2, Rg, Cc, ttv,
                                 w1, b1, w2, b2, isFinal, tnx, CoutNext, rmF, rsF);
  }
  k_combine<<<256, 1024, 0, stream>>>(out, rmF, rsF, Cpool + (size_t)9 * N, out);
}